// Round 1
// baseline (25195.418 us; speedup 1.0000x reference)
//
#include <hip/hip_runtime.h>
#include <math.h>

// Model: GRU enc-dec w/ attention. B=32,S=512,T=128,V=128,L=5,E=512,H=1024,F=2048.
// Strategy (round 0, fp32-correct):
//  - 640-entry embed+fc table; fold into enc gi-table / avc-table / dec gix-table.
//  - Encoder scan: per-step smallM GEMM (h@WhT, K-split partials) + gates kernel.
//  - att_vals & eq-free decoder: per step q,att+softmax,ctx,GRU (5 kernels).
//  - hc[t]=h+ctx recorded; 107-GFLOP MLP runs as batched GEMMs after the scan.
// ws usage ~224 MB; MLP chunk buffers alias dead transposed-weight region.

#define Bb 32
#define Ss 512
#define Tt 128
#define Vv 128
#define Ee 512
#define Hh 1024
#define H3 3072
#define Ff 2048

// ---------------- workspace offsets (floats) ----------------
#define O_ES    0UL                      // enc_states  [B][S][H]   16777216
#define O_AV    16777216UL               // att_vals    [B][S][H]   16777216
#define O_HC    33554432UL               // hc          [T][B][H]    4194304
#define O_EMBFC 37748736UL               // embfc       [640][512]    327680
#define O_GITAB 38076416UL               // enc gi tab  [640][3072]  1966080
#define O_AVTAB 40042496UL               // avc tab     [640][1024]   655360
#define O_DGIXT 40697856UL               // dec gix tab [128][3072]   393216
#define O_XCAT  41091072UL               // xcat        [640][1024]   655360
#define O_WHTE  41746432UL               // enc_Wh^T    [1024][3072] 3145728  (aliased by A1c in MLP)
#define O_WQT   44892160UL               // Wq^T        [1024][1024] 1048576
#define O_WICT  45940736UL               // dec_Wi_ctx^T[1024][3072] 3145728  (aliased by A2c in MLP)
#define O_WHDT  49086464UL               // dec_Wh^T    [1024][3072] 3145728
#define O_PENC  52232192UL               // gh partials [16][32][3072] 1572864 (enc; reused as dec ghP)
#define O_QP    53805056UL               // q partials  [16][32][1024]  524288
#define O_GIP   54329344UL               // gi partials [16][32][3072] 1572864
#define O_CTX   55902208UL               // ctx   [32][1024]  32768
#define O_DECH  55934976UL               // dec h [32][1024]  32768
#define O_ATTL  55967744UL               // att logits [32][512] 16384
// total 55984128 floats = 223.94 MB

// ---------------- xcat builder ----------------
__global__ void k_xcat(const float* __restrict__ ce, const float* __restrict__ le,
                       float* __restrict__ xcat) {
  int row = blockIdx.x;            // l*128 + c
  int l = row >> 7, c = row & 127;
  int i = threadIdx.x * 4;
  float4 v;
  if (i < 512) v = *(const float4*)(ce + c * 512 + i);
  else         v = *(const float4*)(le + l * 512 + (i - 512));
  *(float4*)(xcat + (size_t)row * 1024 + i) = v;
}

// ---------------- transpose: out[c*rows + r] = in[r*rstride + c] ----------------
__global__ void k_transpose(const float* __restrict__ in, int rstride, int rows,
                            float* __restrict__ out) {
  __shared__ float t[32][33];
  int c0 = blockIdx.x * 32, r0 = blockIdx.y * 32;
  int tx = threadIdx.x, ty = threadIdx.y;
  for (int i = ty; i < 32; i += 8)
    t[i][tx] = in[(size_t)(r0 + i) * rstride + c0 + tx];
  __syncthreads();
  for (int i = ty; i < 32; i += 8)
    out[(size_t)(c0 + i) * rows + r0 + tx] = t[tx][i];
}

// ---------------- big tiled GEMM: C[M,N] = A[M,K] @ W[N,K]^T ----------------
// EPI: 0 plain, 1 += avc_tab[lang*128+char][col] (att_vals), 2 scatter to scores out
template <int EPI, bool RELU, bool BIAS>
__global__ __launch_bounds__(256) void k_gemm(
    const float* __restrict__ A, int lda,
    const float* __restrict__ W, int ldw,
    const float* __restrict__ bias,
    float* __restrict__ C, int ldc, int K,
    const float* __restrict__ avtab, const int* __restrict__ gl,
    const int* __restrict__ gc, int r0, float* __restrict__ out2) {
  __shared__ float As[8][128];
  __shared__ float Ws[8][128];
  int tid = threadIdx.x;
  int n0 = blockIdx.x * 128, m0 = blockIdx.y * 128;
  int tx = tid & 15, ty = tid >> 4;
  int lrow = tid >> 1;
  int lseg = (tid & 1) * 4;
  const float* Ap = A + (size_t)(m0 + lrow) * lda + lseg;
  const float* Wp = W + (size_t)(n0 + lrow) * ldw + lseg;
  float acc[8][8];
#pragma unroll
  for (int i = 0; i < 8; ++i)
#pragma unroll
    for (int j = 0; j < 8; ++j) acc[i][j] = 0.f;

  for (int kt = 0; kt < K; kt += 8) {
    float4 av = *(const float4*)(Ap + kt);
    float4 wv = *(const float4*)(Wp + kt);
    __syncthreads();
    As[lseg + 0][lrow] = av.x; As[lseg + 1][lrow] = av.y;
    As[lseg + 2][lrow] = av.z; As[lseg + 3][lrow] = av.w;
    Ws[lseg + 0][lrow] = wv.x; Ws[lseg + 1][lrow] = wv.y;
    Ws[lseg + 2][lrow] = wv.z; Ws[lseg + 3][lrow] = wv.w;
    __syncthreads();
#pragma unroll
    for (int kk = 0; kk < 8; ++kk) {
      float a[8], b[8];
      *(float4*)(a + 0) = *(const float4*)(&As[kk][ty * 8 + 0]);
      *(float4*)(a + 4) = *(const float4*)(&As[kk][ty * 8 + 4]);
      *(float4*)(b + 0) = *(const float4*)(&Ws[kk][tx * 8 + 0]);
      *(float4*)(b + 4) = *(const float4*)(&Ws[kk][tx * 8 + 4]);
#pragma unroll
      for (int i = 0; i < 8; ++i)
#pragma unroll
        for (int j = 0; j < 8; ++j) acc[i][j] = fmaf(a[i], b[j], acc[i][j]);
    }
  }
#pragma unroll
  for (int i = 0; i < 8; ++i) {
    int r = m0 + ty * 8 + i;
#pragma unroll
    for (int j = 0; j < 8; ++j) {
      int c = n0 + tx * 8 + j;
      float v = acc[i][j];
      if (BIAS) v += bias[c];
      if (RELU) v = fmaxf(v, 0.f);
      if (EPI == 0) {
        C[(size_t)r * ldc + c] = v;
      } else if (EPI == 1) {
        int cl = gl[r] * 128 + gc[r];
        C[(size_t)r * ldc + c] = v + avtab[(size_t)cl * 1024 + c];
      } else {
        int rr = r0 + r;
        int bb2 = rr & 31, tt = rr >> 5;
        out2[(size_t)bb2 * (Tt * Vv) + tt * Vv + c] = v;
      }
    }
  }
}

// ---------------- small-M (M=32) GEMM with K-split partials ----------------
// P[kc][b][n] += A[b][k0..k0+63] . WT[k0..k0+63][n]   (WT is K x N, coalesced)
// grid: (N/256, 16, nz); block 256. Optionally (kc==0) folds hc[t] = h + ctx.
__global__ __launch_bounds__(256) void k_smallM(
    const float* __restrict__ A0, int sA0, const float* __restrict__ W0, float* __restrict__ P0,
    const float* __restrict__ A1, int sA1, const float* __restrict__ W1, float* __restrict__ P1,
    int N, int hcfold, const float* __restrict__ hch, const float* __restrict__ hcc,
    float* __restrict__ hco) {
  int z = blockIdx.z;
  const float* A = z ? A1 : A0;
  int sA = z ? sA1 : sA0;
  const float* W = z ? W1 : W0;
  float* P = z ? P1 : P0;
  int n0 = blockIdx.x * 256;
  int kc = blockIdx.y;
  int k0 = kc * 64;
  int tid = threadIdx.x;
  __shared__ float hs[32][64];
  {
    int f = tid * 8;
    int b = f >> 6, kk = f & 63;
    const float* src = A + (size_t)b * sA + k0 + kk;
    float4 v0 = *(const float4*)(src);
    float4 v1 = *(const float4*)(src + 4);
    *(float4*)&hs[b][kk] = v0;
    *(float4*)&hs[b][kk + 4] = v1;
  }
  int j = n0 + tid;
  float wreg[64];
#pragma unroll
  for (int k = 0; k < 64; ++k) wreg[k] = W[(size_t)(k0 + k) * N + j];
  __syncthreads();
  float acc[32];
#pragma unroll
  for (int b = 0; b < 32; ++b) acc[b] = 0.f;
#pragma unroll
  for (int k4 = 0; k4 < 16; ++k4) {
#pragma unroll
    for (int b = 0; b < 32; ++b) {
      float4 h4 = *(const float4*)&hs[b][k4 * 4];
      float t0 = fmaf(wreg[k4 * 4 + 0], h4.x, acc[b]);
      float t1 = fmaf(wreg[k4 * 4 + 1], h4.y, t0);
      float t2 = fmaf(wreg[k4 * 4 + 2], h4.z, t1);
      acc[b] = fmaf(wreg[k4 * 4 + 3], h4.w, t2);
    }
  }
#pragma unroll
  for (int b = 0; b < 32; ++b) P[(size_t)(kc * 32 + b) * N + j] = acc[b];
  if (hcfold && kc == 0) {
#pragma unroll
    for (int b = 0; b < 32; ++b)
      hco[(size_t)b * Hh + j] = hch[(size_t)b * Hh + j] + hcc[(size_t)b * Hh + j];
  }
}

// ---------------- encoder gates + h update (writes enc_states[:,s,:]) ----------------
__global__ void k_gates_enc(float* __restrict__ es, const float* __restrict__ P,
                            const float* __restrict__ gitab, const int* __restrict__ sc,
                            const int* __restrict__ sl, const float* __restrict__ bh,
                            int s, int first) {
  int idx = blockIdx.x * 256 + threadIdx.x;
  int b = idx >> 10, j = idx & 1023;
  float ghr = bh[j], ghz = bh[1024 + j], ghn = bh[2048 + j];
  if (!first) {
#pragma unroll
    for (int kc = 0; kc < 16; ++kc) {
      const float* p = P + (size_t)(kc * 32 + b) * H3 + j;
      ghr += p[0]; ghz += p[1024]; ghn += p[2048];
    }
  }
  int cl = sl[b * Ss + s] * 128 + sc[b * Ss + s];
  const float* gi = gitab + (size_t)cl * H3 + j;
  float gir = gi[0], giz = gi[1024], gin = gi[2048];
  float r = 1.f / (1.f + expf(-(gir + ghr)));
  float z = 1.f / (1.f + expf(-(giz + ghz)));
  float n = tanhf(gin + r * ghn);
  float hold = first ? 0.f : es[(size_t)(b * Ss + (s - 1)) * Hh + j];
  es[(size_t)(b * Ss + s) * Hh + j] = (1.f - z) * n + z * hold;
}

// ---------------- decoder gates + h update (in place) ----------------
__global__ void k_gates_dec(float* __restrict__ h, const float* __restrict__ giP,
                            const float* __restrict__ ghP, const float* __restrict__ dgixt,
                            const int* __restrict__ tgt, const float* __restrict__ bh,
                            int t, int hzero, int usestart) {
  int idx = blockIdx.x * 256 + threadIdx.x;
  int b = idx >> 10, j = idx & 1023;
  float gir = 0.f, giz = 0.f, gin = 0.f;
#pragma unroll
  for (int kc = 0; kc < 16; ++kc) {
    const float* p = giP + (size_t)(kc * 32 + b) * H3 + j;
    gir += p[0]; giz += p[1024]; gin += p[2048];
  }
  float ghr = bh[j], ghz = bh[1024 + j], ghn = bh[2048 + j];
  if (!hzero) {
#pragma unroll
    for (int kc = 0; kc < 16; ++kc) {
      const float* p = ghP + (size_t)(kc * 32 + b) * H3 + j;
      ghr += p[0]; ghz += p[1024]; ghn += p[2048];
    }
  }
  int c = usestart ? 1 : tgt[b * Tt + t];
  const float* gx = dgixt + (size_t)c * H3 + j;
  gir += gx[0]; giz += gx[1024]; gin += gx[2048];
  float r = 1.f / (1.f + expf(-(gir + ghr)));
  float z = 1.f / (1.f + expf(-(giz + ghz)));
  float n = tanhf(gin + r * ghn);
  float hold = hzero ? 0.f : h[idx];
  h[idx] = (1.f - z) * n + z * hold;
}

// ---------------- ctx0 = enc_states[:, S-1, :] ----------------
__global__ void k_ctx0(const float* __restrict__ es, float* __restrict__ ctx) {
  int idx = blockIdx.x * 256 + threadIdx.x;
  int b = idx >> 10, j = idx & 1023;
  ctx[idx] = es[(size_t)(b * Ss + (Ss - 1)) * Hh + j];
}

// ---------------- attention logits: att[b,s] = es[b,s,:] . q[b,:] ----------------
// grid (32, 8), block 256. q summed from 16 partials into LDS.
__global__ __launch_bounds__(256) void k_att(const float* __restrict__ qP,
                                             const float* __restrict__ es,
                                             float* __restrict__ attL) {
  int b = blockIdx.x, s0 = blockIdx.y * 64;
  __shared__ float q[1024];
  int tid = threadIdx.x;
#pragma unroll
  for (int rep = 0; rep < 4; ++rep) {
    int jj = rep * 256 + tid;
    float v = 0.f;
#pragma unroll
    for (int kc = 0; kc < 16; ++kc) v += qP[(size_t)(kc * 32 + b) * Hh + jj];
    q[jj] = v;
  }
  __syncthreads();
  int sg = tid >> 2, li = tid & 3;
  int s = s0 + sg;
  const float* er = es + (size_t)(b * Ss + s) * Hh;
  float acc = 0.f;
#pragma unroll 8
  for (int i = 0; i < 64; ++i) {
    int k = li * 4 + i * 16;
    float4 e4 = *(const float4*)(er + k);
    float4 q4 = *(const float4*)(q + k);
    acc += e4.x * q4.x + e4.y * q4.y + e4.z * q4.z + e4.w * q4.w;
  }
  acc += __shfl_xor(acc, 1);
  acc += __shfl_xor(acc, 2);
  if (li == 0) attL[b * Ss + s] = acc;
}

// ---------------- softmax + ctx = w @ att_vals ----------------
// grid (8, 32): jtile, b. block 256 = 128 j x 2 s-halves.
__global__ __launch_bounds__(256) void k_ctxsm(const float* __restrict__ attL,
                                               const float* __restrict__ av,
                                               float* __restrict__ ctx) {
  int jt = blockIdx.x, b = blockIdx.y;
  __shared__ float w[512];
  __shared__ float wm[4];
  __shared__ float wsm[4];
  __shared__ float red2[128];
  int tid = threadIdx.x;
  float a0 = attL[b * Ss + tid * 2];
  float a1 = attL[b * Ss + tid * 2 + 1];
  float m = fmaxf(a0, a1);
  for (int d = 1; d < 64; d <<= 1) m = fmaxf(m, __shfl_xor(m, d));
  if ((tid & 63) == 0) wm[tid >> 6] = m;
  __syncthreads();
  m = fmaxf(fmaxf(wm[0], wm[1]), fmaxf(wm[2], wm[3]));
  float e0 = expf(a0 - m), e1 = expf(a1 - m);
  w[tid * 2] = e0;
  w[tid * 2 + 1] = e1;
  float ssum = e0 + e1;
  for (int d = 1; d < 64; d <<= 1) ssum += __shfl_xor(ssum, d);
  if ((tid & 63) == 0) wsm[tid >> 6] = ssum;
  __syncthreads();
  float scale = 1.f / (wsm[0] + wsm[1] + wsm[2] + wsm[3]);
  int j = jt * 128 + (tid & 127);
  int sh = tid >> 7;
  const float* avp = av + (size_t)(b * Ss + sh * 256) * Hh + j;
  float acc = 0.f;
#pragma unroll 16
  for (int s = 0; s < 256; ++s) acc += w[sh * 256 + s] * avp[(size_t)s * Hh];
  if (sh == 1) red2[tid & 127] = acc;
  __syncthreads();
  if (sh == 0) ctx[b * Hh + j] = (acc + red2[tid & 127]) * scale;
}

// ---------------- host ----------------
extern "C" void kernel_launch(void* const* d_in, const int* in_sizes, int n_in,
                              void* d_out, int out_size, void* d_ws, size_t ws_size,
                              hipStream_t stream) {
  (void)in_sizes; (void)n_in; (void)out_size; (void)ws_size;
  const int*   src_chars = (const int*)d_in[0];
  const int*   src_langs = (const int*)d_in[1];
  const int*   tgt_chars = (const int*)d_in[2];
  const float* char_emb  = (const float*)d_in[3];
  const float* lang_emb  = (const float*)d_in[4];
  const float* fc_W  = (const float*)d_in[5];
  const float* fc_b  = (const float*)d_in[6];
  const float* enc_Wi = (const float*)d_in[7];
  const float* enc_Wh = (const float*)d_in[8];
  const float* enc_bi = (const float*)d_in[9];
  const float* enc_bh = (const float*)d_in[10];
  const float* dec_Wi = (const float*)d_in[11];
  const float* dec_Wh = (const float*)d_in[12];
  const float* dec_bi = (const float*)d_in[13];
  const float* dec_bh = (const float*)d_in[14];
  const float* Wq  = (const float*)d_in[15];
  const float* Wk  = (const float*)d_in[16];
  const float* Wcs = (const float*)d_in[17];
  const float* W1 = (const float*)d_in[18];
  const float* b1 = (const float*)d_in[19];
  const float* W2 = (const float*)d_in[20];
  const float* b2 = (const float*)d_in[21];
  const float* W3 = (const float*)d_in[22];
  float* out = (float*)d_out;

  float* ws = (float*)d_ws;
  float* es    = ws + O_ES;
  float* av    = ws + O_AV;
  float* hc    = ws + O_HC;
  float* embfc = ws + O_EMBFC;
  float* gitab = ws + O_GITAB;
  float* avtab = ws + O_AVTAB;
  float* dgixt = ws + O_DGIXT;
  float* xcat  = ws + O_XCAT;
  float* WhTe  = ws + O_WHTE;
  float* WqT   = ws + O_WQT;
  float* WicT  = ws + O_WICT;
  float* WhdT  = ws + O_WHDT;
  float* Penc  = ws + O_PENC;   // also decoder ghP
  float* qP    = ws + O_QP;
  float* giP   = ws + O_GIP;
  float* ctx   = ws + O_CTX;
  float* dech  = ws + O_DECH;
  float* attL  = ws + O_ATTL;
  float* A1c = ws + O_WHTE;     // MLP chunk buffers alias dead transposed weights
  float* A2c = ws + O_WICT;

  dim3 blk256(256);

  // ---- setup: tables + transposes ----
  k_xcat<<<640, blk256, 0, stream>>>(char_emb, lang_emb, xcat);
  k_transpose<<<dim3(32, 96), dim3(32, 8), 0, stream>>>(enc_Wh, Hh, H3, WhTe);
  k_transpose<<<dim3(32, 32), dim3(32, 8), 0, stream>>>(Wq, Hh, Hh, WqT);
  k_transpose<<<dim3(32, 96), dim3(32, 8), 0, stream>>>(dec_Wi + Ee, Ee + Hh, H3, WicT);
  k_transpose<<<dim3(32, 96), dim3(32, 8), 0, stream>>>(dec_Wh, Hh, H3, WhdT);
  // embfc = xcat @ fc_W^T + fc_b    (640 x 512, K=1024)
  k_gemm<0, false, true><<<dim3(4, 5), blk256, 0, stream>>>(
      xcat, 1024, fc_W, 1024, fc_b, embfc, 512, 1024, nullptr, nullptr, nullptr, 0, nullptr);
  // enc gi table = embfc @ enc_Wi^T + enc_bi  (640 x 3072, K=512)
  k_gemm<0, false, true><<<dim3(24, 5), blk256, 0, stream>>>(
      embfc, 512, enc_Wi, 512, enc_bi, gitab, H3, 512, nullptr, nullptr, nullptr, 0, nullptr);
  // avc table = embfc @ Wcs^T  (640 x 1024, K=512)
  k_gemm<0, false, false><<<dim3(8, 5), blk256, 0, stream>>>(
      embfc, 512, Wcs, 512, nullptr, avtab, Hh, 512, nullptr, nullptr, nullptr, 0, nullptr);
  // dec gix table = embfc[l=4 rows] @ dec_Wi[:, :E]^T + dec_bi (128 x 3072, K=512)
  k_gemm<0, false, true><<<dim3(24, 1), blk256, 0, stream>>>(
      embfc + 512 * 512, 512, dec_Wi, Ee + Hh, dec_bi, dgixt, H3, 512,
      nullptr, nullptr, nullptr, 0, nullptr);

  // ---- encoder scan ----
  for (int s = 0; s < Ss; ++s) {
    if (s > 0) {
      k_smallM<<<dim3(12, 16, 1), blk256, 0, stream>>>(
          es + (size_t)(s - 1) * Hh, Ss * Hh, WhTe, Penc,
          nullptr, 0, nullptr, nullptr, H3, 0, nullptr, nullptr, nullptr);
    }
    k_gates_enc<<<128, blk256, 0, stream>>>(es, Penc, gitab, src_chars, src_langs,
                                            enc_bh, s, s == 0 ? 1 : 0);
  }

  // ---- att_vals = avc_tab[cl] + enc_states @ Wk^T  (16384 x 1024, K=1024) ----
  k_gemm<1, false, false><<<dim3(8, 128), blk256, 0, stream>>>(
      es, Hh, Wk, Hh, nullptr, av, Hh, Hh, avtab, src_langs, src_chars, 0, nullptr);

  // ---- decoder init: ctx0, dec_h = gru(0, [start_emb, ctx0]) ----
  k_ctx0<<<128, blk256, 0, stream>>>(es, ctx);
  k_smallM<<<dim3(12, 16, 1), blk256, 0, stream>>>(
      ctx, Hh, WicT, giP, nullptr, 0, nullptr, nullptr, H3, 0, nullptr, nullptr, nullptr);
  k_gates_dec<<<128, blk256, 0, stream>>>(dech, giP, Penc, dgixt, tgt_chars, dec_bh,
                                          0, 1, 1);

  // ---- decoder scan ----
  for (int t = 0; t < Tt; ++t) {
    // q partials (+ record hc[t] = h + ctx)
    k_smallM<<<dim3(4, 16, 1), blk256, 0, stream>>>(
        dech, Hh, WqT, qP, nullptr, 0, nullptr, nullptr, Hh,
        1, dech, ctx, hc + (size_t)t * Bb * Hh);
    k_att<<<dim3(32, 8), blk256, 0, stream>>>(qP, es, attL);
    k_ctxsm<<<dim3(8, 32), blk256, 0, stream>>>(attL, av, ctx);
    if (t < Tt - 1) {
      k_smallM<<<dim3(12, 16, 2), blk256, 0, stream>>>(
          ctx, Hh, WicT, giP, dech, Hh, WhdT, Penc, H3, 0, nullptr, nullptr, nullptr);
      k_gates_dec<<<128, blk256, 0, stream>>>(dech, giP, Penc, dgixt, tgt_chars,
                                              dec_bh, t, 0, 0);
    }
  }

  // ---- MLP: scores = relu(relu(hc@W1^T+b1)@W2^T+b2)@W3^T, chunked 1024 rows ----
  for (int c = 0; c < 4; ++c) {
    const float* hcc = hc + (size_t)c * 1024 * Hh;
    k_gemm<0, true, true><<<dim3(32, 8), blk256, 0, stream>>>(
        hcc, Hh, W1, Hh, b1, A1c, 2 * Ff, Hh, nullptr, nullptr, nullptr, 0, nullptr);
    k_gemm<0, true, true><<<dim3(16, 8), blk256, 0, stream>>>(
        A1c, 2 * Ff, W2, 2 * Ff, b2, A2c, Ff, 2 * Ff, nullptr, nullptr, nullptr, 0, nullptr);
    k_gemm<2, false, false><<<dim3(1, 8), blk256, 0, stream>>>(
        A2c, Ff, W3, Ff, nullptr, nullptr, 0, Ff, nullptr, nullptr, nullptr,
        c * 1024, out);
  }
}

// Round 3
// 9582.373 us; speedup vs baseline: 2.6294x; 2.6294x over previous
//
#include <hip/hip_runtime.h>
#include <math.h>

// GRU enc-dec w/ attention. B=32,S=512,T=128,V=128,L=5,E=512,H=1024,F=2048.
// R2: fix k_bgemm LDS staging (R1 loaded only half the k-range -> NaN);
// pad k_bgemm LDS stride 32->40 elems (8-way -> 2-way bank conflicts).

#define Bb 32
#define Ss 512
#define Tt 128
#define Vv 128
#define Hh 1024
#define H3 3072
#define APAD 40

typedef __attribute__((ext_vector_type(8))) short bf16x8;
typedef __attribute__((ext_vector_type(4))) float f32x4;

__device__ inline f32x4 mfma_bf16(bf16x8 a, bf16x8 b, f32x4 c) {
  return __builtin_amdgcn_mfma_f32_16x16x32_bf16(a, b, c, 0, 0, 0);
}
__device__ inline unsigned short f2bf(float f) {
  unsigned u = __builtin_bit_cast(unsigned, f);
  unsigned r = (u + 0x7fffu + ((u >> 16) & 1u)) >> 16;
  return (unsigned short)r;
}
__device__ inline float lof(unsigned u) { return __builtin_bit_cast(float, u << 16); }
__device__ inline float hif(unsigned u) { return __builtin_bit_cast(float, u & 0xffff0000u); }
__device__ inline float bf2f(unsigned short h) {
  return __builtin_bit_cast(float, ((unsigned)h) << 16);
}

// ---------------- workspace offsets (BYTES) ----------------
#define O_ESBF   0UL            // es bf16      [B*S][1024]  32MB
#define O_ESQ    33554432UL     // esq bf16     [B*S][1024]  32MB  (aliased: G1 in MLP)
#define O_AVBF   67108864UL     // av bf16      [B*S][1024]  32MB  (aliased: G2 in MLP)
#define O_HCBF   100663296UL    // hc bf16      [T*B][1024]   8MB
#define O_WHE    109051904UL    // enc_Wh bf16  [3072][1024]  6MB
#define O_WHD    115343360UL    // dec_Wh bf16  6MB
#define O_WIC    121634816UL    // dec_Wi ctx-cols bf16 [3072][1024] 6MB
#define O_WKB    127926272UL    // Wk bf16 [1024][1024] 2MB
#define O_WQT    130023424UL    // Wq^T bf16 [1024][1024] 2MB
#define O_W1B    132120576UL    // W1 bf16 [4096][1024] 8MB
#define O_W2B    140509184UL    // W2 bf16 [2048][4096] 16MB
#define O_W3B    157286400UL    // W3 bf16 [128][2048] 0.5MB
#define O_XCAT   157810688UL    // fp32 [640][1024]
#define O_EMBFC  160432128UL    // fp32 [640][512]
#define O_GITAB  161742848UL    // fp32 [640][3072]
#define O_AVTAB  169607168UL    // fp32 [640][1024]
#define O_DGIXT  172228608UL    // fp32 [128][3072]
#define O_GH     173801472UL    // fp32 [32][3072]
#define O_GI     174194688UL    // fp32 [32][3072]
#define O_H      174587904UL    // fp32 [32][1024]
#define O_HBF    174718976UL    // bf16 [32][1024]
#define O_CTX    174784512UL    // fp32 [32][1024]
#define O_CTXBF  174915584UL    // bf16 [32][1024]
#define O_ATTL   174981120UL    // fp32 [32][512]
// total ~167MB

// ---------------- setup helpers ----------------
__global__ void k_xcat(const float* __restrict__ ce, const float* __restrict__ le,
                       float* __restrict__ xcat) {
  int row = blockIdx.x;  // l*128 + c
  int l = row >> 7, c = row & 127;
  int i = threadIdx.x * 4;
  float4 v;
  if (i < 512) v = *(const float4*)(ce + c * 512 + i);
  else         v = *(const float4*)(le + l * 512 + (i - 512));
  *(float4*)(xcat + (size_t)row * 1024 + i) = v;
}

__global__ void k_cvt(const float* __restrict__ src, int ld, int lc,
                      unsigned short* __restrict__ dst) {
  size_t i = ((size_t)blockIdx.x * 256 + threadIdx.x) * 8;
  size_t r = i >> lc;
  int c = (int)(i & ((1u << lc) - 1));
  const float* s = src + r * (size_t)ld + c;
  float4 v0 = *(const float4*)s;
  float4 v1 = *(const float4*)(s + 4);
  union { unsigned short us[8]; uint4 u; } o;
  o.us[0] = f2bf(v0.x); o.us[1] = f2bf(v0.y); o.us[2] = f2bf(v0.z); o.us[3] = f2bf(v0.w);
  o.us[4] = f2bf(v1.x); o.us[5] = f2bf(v1.y); o.us[6] = f2bf(v1.z); o.us[7] = f2bf(v1.w);
  *(uint4*)(dst + i) = o.u;
}

__global__ void k_transcvt(const float* __restrict__ in, unsigned short* __restrict__ out) {
  __shared__ float t[32][33];
  int c0 = blockIdx.x * 32, r0 = blockIdx.y * 32;
  int tx = threadIdx.x, ty = threadIdx.y;
  for (int i = ty; i < 32; i += 8)
    t[i][tx] = in[(size_t)(r0 + i) * 1024 + c0 + tx];
  __syncthreads();
  for (int i = ty; i < 32; i += 8)
    out[(size_t)(c0 + i) * 1024 + r0 + tx] = f2bf(t[tx][i]);
}

// ---------------- fp32 tiled GEMM (setup tables only): C=A@W^T ----------------
template <bool BIAS>
__global__ __launch_bounds__(256) void k_gemm(
    const float* __restrict__ A, int lda, const float* __restrict__ W, int ldw,
    const float* __restrict__ bias, float* __restrict__ C, int ldc, int K) {
  __shared__ float As[8][128];
  __shared__ float Ws[8][128];
  int tid = threadIdx.x;
  int n0 = blockIdx.x * 128, m0 = blockIdx.y * 128;
  int tx = tid & 15, ty = tid >> 4;
  int lrow = tid >> 1, lseg = (tid & 1) * 4;
  const float* Ap = A + (size_t)(m0 + lrow) * lda + lseg;
  const float* Wp = W + (size_t)(n0 + lrow) * ldw + lseg;
  float acc[8][8];
#pragma unroll
  for (int i = 0; i < 8; ++i)
#pragma unroll
    for (int j = 0; j < 8; ++j) acc[i][j] = 0.f;
  for (int kt = 0; kt < K; kt += 8) {
    float4 av = *(const float4*)(Ap + kt);
    float4 wv = *(const float4*)(Wp + kt);
    __syncthreads();
    As[lseg + 0][lrow] = av.x; As[lseg + 1][lrow] = av.y;
    As[lseg + 2][lrow] = av.z; As[lseg + 3][lrow] = av.w;
    Ws[lseg + 0][lrow] = wv.x; Ws[lseg + 1][lrow] = wv.y;
    Ws[lseg + 2][lrow] = wv.z; Ws[lseg + 3][lrow] = wv.w;
    __syncthreads();
#pragma unroll
    for (int kk = 0; kk < 8; ++kk) {
      float a[8], b[8];
      *(float4*)(a + 0) = *(const float4*)(&As[kk][ty * 8 + 0]);
      *(float4*)(a + 4) = *(const float4*)(&As[kk][ty * 8 + 4]);
      *(float4*)(b + 0) = *(const float4*)(&Ws[kk][tx * 8 + 0]);
      *(float4*)(b + 4) = *(const float4*)(&Ws[kk][tx * 8 + 4]);
#pragma unroll
      for (int i = 0; i < 8; ++i)
#pragma unroll
        for (int j = 0; j < 8; ++j) acc[i][j] = fmaf(a[i], b[j], acc[i][j]);
    }
  }
#pragma unroll
  for (int i = 0; i < 8; ++i) {
    int r = m0 + ty * 8 + i;
#pragma unroll
    for (int j = 0; j < 8; ++j) {
      int c = n0 + tx * 8 + j;
      float v = acc[i][j];
      if (BIAS) v += bias[c];
      C[(size_t)r * ldc + c] = v;
    }
  }
}

// ---------------- bf16 MFMA GEMM: C[M,N] = A[M,K] @ W[N,K]^T ----------------
// EPI: 0 store bf16; 1 +=avtab[lang*128+char][col], store bf16; 2 fp32 scatter to out
template <int EPI, bool RELU, bool BIAS>
__global__ __launch_bounds__(256) void k_bgemm(
    const unsigned short* __restrict__ A, int lda,
    const unsigned short* __restrict__ W, int ldw,
    const float* __restrict__ bias, void* __restrict__ Cout, int ldc, int K,
    const float* __restrict__ avtab, const int* __restrict__ gl,
    const int* __restrict__ gc) {
  __shared__ unsigned short As[128 * APAD];
  __shared__ unsigned short Bs[128 * APAD];
  int tid = threadIdx.x;
  int n0 = blockIdx.x * 128, m0 = blockIdx.y * 128;
  int w = tid >> 6, l = tid & 63;
  int mw = (w & 1) * 64, nw = (w >> 1) * 64;
  int lrow = tid >> 1, lk = (tid & 1) * 16;
  const unsigned short* Ap = A + (size_t)(m0 + lrow) * lda + lk;
  const unsigned short* Wp = W + (size_t)(n0 + lrow) * ldw + lk;
  int fr = l & 15, fk = (l >> 4) * 8;
  f32x4 acc[4][4];
#pragma unroll
  for (int i = 0; i < 4; ++i)
#pragma unroll
    for (int j = 0; j < 4; ++j) acc[i][j] = (f32x4){0.f, 0.f, 0.f, 0.f};
  for (int kt = 0; kt < K; kt += 32) {
    uint4 a0 = *(const uint4*)(Ap + kt);
    uint4 a1 = *(const uint4*)(Ap + kt + 8);
    uint4 b0 = *(const uint4*)(Wp + kt);
    uint4 b1 = *(const uint4*)(Wp + kt + 8);
    __syncthreads();
    *(uint4*)&As[lrow * APAD + lk] = a0;
    *(uint4*)&As[lrow * APAD + lk + 8] = a1;
    *(uint4*)&Bs[lrow * APAD + lk] = b0;
    *(uint4*)&Bs[lrow * APAD + lk + 8] = b1;
    __syncthreads();
    bf16x8 af[4], bfg[4];
#pragma unroll
    for (int i = 0; i < 4; ++i) af[i] = *(const bf16x8*)&As[(mw + i * 16 + fr) * APAD + fk];
#pragma unroll
    for (int j = 0; j < 4; ++j) bfg[j] = *(const bf16x8*)&Bs[(nw + j * 16 + fr) * APAD + fk];
#pragma unroll
    for (int i = 0; i < 4; ++i)
#pragma unroll
      for (int j = 0; j < 4; ++j) acc[i][j] = mfma_bf16(af[i], bfg[j], acc[i][j]);
  }
#pragma unroll
  for (int i = 0; i < 4; ++i)
#pragma unroll
    for (int j = 0; j < 4; ++j) {
      int col = n0 + nw + j * 16 + fr;
#pragma unroll
      for (int r = 0; r < 4; ++r) {
        int row = m0 + mw + i * 16 + (l >> 4) * 4 + r;
        float v = acc[i][j][r];
        if (BIAS) v += bias[col];
        if (RELU) v = fmaxf(v, 0.f);
        if (EPI == 0) {
          ((unsigned short*)Cout)[(size_t)row * ldc + col] = f2bf(v);
        } else if (EPI == 1) {
          int cl = gl[row] * 128 + gc[row];
          ((unsigned short*)Cout)[(size_t)row * ldc + col] =
              f2bf(v + avtab[(size_t)cl * 1024 + col]);
        } else {
          int tt = row >> 5, bb = row & 31;
          ((float*)Cout)[(size_t)bb * (Tt * Vv) + tt * Vv + col] = v;
        }
      }
    }
}

// ---------------- M=32 recurrent MFMA GEMM (+ optional fused attention) ----------
// Blocks [0,nrec): C fp32 [32][N] = A_bf[32][1024] @ W_bf[N][1024]^T (64 cols/block)
// Blocks [nrec, nrec+256): att[b,s] = esq_bf[b,s,:].h[b,:] (+ hc-fold on first 4/b)
__global__ __launch_bounds__(256) void k_rec(
    const unsigned short* __restrict__ A, const unsigned short* __restrict__ W,
    float* __restrict__ C, int N, int nrec,
    const unsigned short* __restrict__ esq, const float* __restrict__ h,
    const float* __restrict__ ctx, float* __restrict__ attL,
    unsigned short* __restrict__ hc) {
  __shared__ unsigned short As[32 * 1024];  // 64KB; att branch reuses 4KB as fp32 h
  int tid = threadIdx.x;
  int id = blockIdx.x;
  if (id < nrec) {
    {
      const uint4* src = (const uint4*)A;
      uint4* dst = (uint4*)As;
#pragma unroll
      for (int i = 0; i < 16; ++i) {
        int c = i * 256 + tid;
        int m = c >> 7, kc = c & 127;
        dst[m * 128 + (kc ^ (m & 7))] = src[c];  // XOR-swizzle per 16B chunk
      }
    }
    __syncthreads();
    int w = tid >> 6, l = tid & 63;
    int nb = id * 64 + w * 16;
    int fr = l & 15, fk8 = (l >> 4);  // k-offset = fk8*8
    const unsigned short* Wp = W + (size_t)(nb + fr) * 1024 + fk8 * 8;
    const bf16x8* Asv = (const bf16x8*)As;
    f32x4 acc0 = (f32x4){0.f, 0.f, 0.f, 0.f}, acc1 = acc0;
#pragma unroll 8
    for (int kt = 0; kt < 1024; kt += 32) {
      int kc8 = (kt >> 3) + fk8;
      bf16x8 bw = *(const bf16x8*)(Wp + kt);
      bf16x8 a0 = Asv[fr * 128 + (kc8 ^ (fr & 7))];
      bf16x8 a1 = Asv[(fr + 16) * 128 + (kc8 ^ (fr & 7))];
      acc0 = mfma_bf16(a0, bw, acc0);
      acc1 = mfma_bf16(a1, bw, acc1);
    }
    int col = nb + fr;
    int rb = (l >> 4) * 4;
#pragma unroll
    for (int r = 0; r < 4; ++r) {
      C[(size_t)(rb + r) * N + col] = acc0[r];
      C[(size_t)(rb + r + 16) * N + col] = acc1[r];
    }
  } else {
    float* hs = (float*)As;
    int a = id - nrec, b = a >> 3, sc = a & 7;
    for (int i = tid; i < 1024; i += 256) hs[i] = h[b * 1024 + i];
    __syncthreads();
    if (sc < 4) {
      int j = sc * 256 + tid;
      hc[b * 1024 + j] = f2bf(hs[j] + ctx[b * 1024 + j]);
    }
    int sg = tid >> 2, li = tid & 3;
    int s = sc * 64 + sg;
    const unsigned short* ep = esq + (size_t)(b * 512 + s) * 1024;
    float acc = 0.f;
#pragma unroll 4
    for (int i = 0; i < 32; ++i) {
      int k = (i * 4 + li) * 8;
      uint4 e = *(const uint4*)(ep + k);
      float4 h0 = *(const float4*)&hs[k];
      float4 h1 = *(const float4*)&hs[k + 4];
      acc += lof(e.x) * h0.x + hif(e.x) * h0.y + lof(e.y) * h0.z + hif(e.y) * h0.w +
             lof(e.z) * h1.x + hif(e.z) * h1.y + lof(e.w) * h1.z + hif(e.w) * h1.w;
    }
    acc += __shfl_xor(acc, 1);
    acc += __shfl_xor(acc, 2);
    if (li == 0) attL[b * 512 + s] = acc;
  }
}

// ---------------- encoder gates ----------------
__global__ void k_gates_enc(const float* __restrict__ gh, const float* __restrict__ gitab,
                            const int* __restrict__ sc, const int* __restrict__ sl,
                            const float* __restrict__ bh, float* __restrict__ h,
                            unsigned short* __restrict__ hbf, unsigned short* __restrict__ esb,
                            int s, int first) {
  int idx = blockIdx.x * 256 + threadIdx.x;
  int b = idx >> 10, j = idx & 1023;
  float ghr = bh[j], ghz = bh[1024 + j], ghn = bh[2048 + j];
  if (!first) {
    const float* g = gh + b * H3 + j;
    ghr += g[0]; ghz += g[1024]; ghn += g[2048];
  }
  int cl = sl[b * Ss + s] * 128 + sc[b * Ss + s];
  const float* gi = gitab + (size_t)cl * H3 + j;
  float r = 1.f / (1.f + expf(-(gi[0] + ghr)));
  float z = 1.f / (1.f + expf(-(gi[1024] + ghz)));
  float n = tanhf(gi[2048] + r * ghn);
  float hold = first ? 0.f : h[idx];
  float hn = (1.f - z) * n + z * hold;
  h[idx] = hn;
  unsigned short hb = f2bf(hn);
  hbf[idx] = hb;
  esb[(size_t)(b * Ss + s) * Hh + j] = hb;
}

// ---------------- decoder gates ----------------
__global__ void k_gates_dec(const float* __restrict__ gi, const float* __restrict__ gh,
                            const float* __restrict__ dgixt, const int* __restrict__ tgt,
                            const float* __restrict__ bh, float* __restrict__ h,
                            unsigned short* __restrict__ hbf, int t, int hzero, int usestart) {
  int idx = blockIdx.x * 256 + threadIdx.x;
  int b = idx >> 10, j = idx & 1023;
  const float* gp = gi + b * H3 + j;
  float gir = gp[0], giz = gp[1024], gin = gp[2048];
  float ghr = bh[j], ghz = bh[1024 + j], ghn = bh[2048 + j];
  if (!hzero) {
    const float* g = gh + b * H3 + j;
    ghr += g[0]; ghz += g[1024]; ghn += g[2048];
  }
  int c = usestart ? 1 : tgt[b * Tt + t];
  const float* gx = dgixt + (size_t)c * H3 + j;
  gir += gx[0]; giz += gx[1024]; gin += gx[2048];
  float r = 1.f / (1.f + expf(-(gir + ghr)));
  float z = 1.f / (1.f + expf(-(giz + ghz)));
  float n = tanhf(gin + r * ghn);
  float hold = hzero ? 0.f : h[idx];
  float hn = (1.f - z) * n + z * hold;
  h[idx] = hn;
  hbf[idx] = f2bf(hn);
}

// ---------------- ctx init (ctx = final encoder h) ----------------
__global__ void k_ctxinit(const float* __restrict__ h, float* __restrict__ ctx,
                          unsigned short* __restrict__ ctxbf) {
  int idx = blockIdx.x * 256 + threadIdx.x;
  float v = h[idx];
  ctx[idx] = v;
  ctxbf[idx] = f2bf(v);
}

// ---------------- softmax + ctx = w @ av_bf ----------------
__global__ __launch_bounds__(256) void k_ctxsm(const float* __restrict__ attL,
                                               const unsigned short* __restrict__ av,
                                               float* __restrict__ ctx,
                                               unsigned short* __restrict__ ctxbf) {
  int jt = blockIdx.x, b = blockIdx.y;
  __shared__ float w[512];
  __shared__ float wm[4];
  __shared__ float wsm[4];
  __shared__ float red2[128];
  int tid = threadIdx.x;
  float a0 = attL[b * Ss + tid * 2];
  float a1 = attL[b * Ss + tid * 2 + 1];
  float m = fmaxf(a0, a1);
  for (int d = 1; d < 64; d <<= 1) m = fmaxf(m, __shfl_xor(m, d));
  if ((tid & 63) == 0) wm[tid >> 6] = m;
  __syncthreads();
  m = fmaxf(fmaxf(wm[0], wm[1]), fmaxf(wm[2], wm[3]));
  float e0 = expf(a0 - m), e1 = expf(a1 - m);
  w[tid * 2] = e0;
  w[tid * 2 + 1] = e1;
  float ssum = e0 + e1;
  for (int d = 1; d < 64; d <<= 1) ssum += __shfl_xor(ssum, d);
  if ((tid & 63) == 0) wsm[tid >> 6] = ssum;
  __syncthreads();
  float scale = 1.f / (wsm[0] + wsm[1] + wsm[2] + wsm[3]);
  int j = jt * 128 + (tid & 127);
  int sh = tid >> 7;
  const unsigned short* avp = av + (size_t)(b * Ss + sh * 256) * Hh + j;
  float acc = 0.f;
#pragma unroll 16
  for (int s = 0; s < 256; ++s) acc += w[sh * 256 + s] * bf2f(avp[(size_t)s * Hh]);
  if (sh == 1) red2[tid & 127] = acc;
  __syncthreads();
  if (sh == 0) {
    float v = (acc + red2[tid & 127]) * scale;
    ctx[b * Hh + j] = v;
    ctxbf[b * Hh + j] = f2bf(v);
  }
}

// ---------------- host ----------------
extern "C" void kernel_launch(void* const* d_in, const int* in_sizes, int n_in,
                              void* d_out, int out_size, void* d_ws, size_t ws_size,
                              hipStream_t stream) {
  (void)in_sizes; (void)n_in; (void)out_size; (void)ws_size;
  const int*   src_chars = (const int*)d_in[0];
  const int*   src_langs = (const int*)d_in[1];
  const int*   tgt_chars = (const int*)d_in[2];
  const float* char_emb  = (const float*)d_in[3];
  const float* lang_emb  = (const float*)d_in[4];
  const float* fc_W  = (const float*)d_in[5];
  const float* fc_b  = (const float*)d_in[6];
  const float* enc_Wi = (const float*)d_in[7];
  const float* enc_Wh = (const float*)d_in[8];
  const float* enc_bi = (const float*)d_in[9];
  const float* enc_bh = (const float*)d_in[10];
  const float* dec_Wi = (const float*)d_in[11];
  const float* dec_Wh = (const float*)d_in[12];
  const float* dec_bi = (const float*)d_in[13];
  const float* dec_bh = (const float*)d_in[14];
  const float* Wq  = (const float*)d_in[15];
  const float* Wk  = (const float*)d_in[16];
  const float* Wcs = (const float*)d_in[17];
  const float* W1 = (const float*)d_in[18];
  const float* b1 = (const float*)d_in[19];
  const float* W2 = (const float*)d_in[20];
  const float* b2 = (const float*)d_in[21];
  const float* W3 = (const float*)d_in[22];
  float* out = (float*)d_out;

  char* ws = (char*)d_ws;
  unsigned short* esbf  = (unsigned short*)(ws + O_ESBF);
  unsigned short* esq   = (unsigned short*)(ws + O_ESQ);
  unsigned short* avbf  = (unsigned short*)(ws + O_AVBF);
  unsigned short* hcbf  = (unsigned short*)(ws + O_HCBF);
  unsigned short* WheB  = (unsigned short*)(ws + O_WHE);
  unsigned short* WhdB  = (unsigned short*)(ws + O_WHD);
  unsigned short* WicB  = (unsigned short*)(ws + O_WIC);
  unsigned short* WkB   = (unsigned short*)(ws + O_WKB);
  unsigned short* WqTB  = (unsigned short*)(ws + O_WQT);
  unsigned short* W1B   = (unsigned short*)(ws + O_W1B);
  unsigned short* W2B   = (unsigned short*)(ws + O_W2B);
  unsigned short* W3B   = (unsigned short*)(ws + O_W3B);
  float* xcat   = (float*)(ws + O_XCAT);
  float* embfc  = (float*)(ws + O_EMBFC);
  float* gitab  = (float*)(ws + O_GITAB);
  float* avtab  = (float*)(ws + O_AVTAB);
  float* dgixt  = (float*)(ws + O_DGIXT);
  float* ghbuf  = (float*)(ws + O_GH);
  float* gibuf  = (float*)(ws + O_GI);
  float* h      = (float*)(ws + O_H);
  unsigned short* hbf   = (unsigned short*)(ws + O_HBF);
  float* ctx    = (float*)(ws + O_CTX);
  unsigned short* ctxbf = (unsigned short*)(ws + O_CTXBF);
  float* attL   = (float*)(ws + O_ATTL);
  unsigned short* G1 = esq;   // alias: dead after decoder
  unsigned short* G2 = avbf;  // alias: dead after decoder

  dim3 blk(256);

  // ---- tables (fp32) ----
  k_xcat<<<640, blk, 0, stream>>>(char_emb, lang_emb, xcat);
  k_gemm<true><<<dim3(4, 5), blk, 0, stream>>>(xcat, 1024, fc_W, 1024, fc_b, embfc, 512, 1024);
  k_gemm<true><<<dim3(24, 5), blk, 0, stream>>>(embfc, 512, enc_Wi, 512, enc_bi, gitab, H3, 512);
  k_gemm<false><<<dim3(8, 5), blk, 0, stream>>>(embfc, 512, Wcs, 512, nullptr, avtab, Hh, 512);
  k_gemm<true><<<dim3(24, 1), blk, 0, stream>>>(embfc + 512 * 512, 512, dec_Wi, 1536, dec_bi,
                                                dgixt, H3, 512);
  // ---- weight conversions ----
  k_cvt<<<1536, blk, 0, stream>>>(enc_Wh, 1024, 10, WheB);
  k_cvt<<<1536, blk, 0, stream>>>(dec_Wh, 1024, 10, WhdB);
  k_cvt<<<1536, blk, 0, stream>>>(dec_Wi + 512, 1536, 10, WicB);
  k_cvt<<<512,  blk, 0, stream>>>(Wk, 1024, 10, WkB);
  k_cvt<<<2048, blk, 0, stream>>>(W1, 1024, 10, W1B);
  k_cvt<<<4096, blk, 0, stream>>>(W2, 4096, 12, W2B);
  k_cvt<<<128,  blk, 0, stream>>>(W3, 2048, 11, W3B);
  k_transcvt<<<dim3(32, 32), dim3(32, 8), 0, stream>>>(Wq, WqTB);

  // ---- encoder scan ----
  for (int s = 0; s < Ss; ++s) {
    if (s > 0)
      k_rec<<<48, blk, 0, stream>>>(hbf, WheB, ghbuf, H3, 48,
                                    nullptr, nullptr, nullptr, nullptr, nullptr);
    k_gates_enc<<<128, blk, 0, stream>>>(ghbuf, gitab, src_chars, src_langs, enc_bh,
                                         h, hbf, esbf, s, s == 0 ? 1 : 0);
  }

  // ---- esq = es @ Wq (for att = esq.h); av = es @ Wk^T + avtab ----
  k_bgemm<0, false, false><<<dim3(8, 128), blk, 0, stream>>>(
      esbf, 1024, WqTB, 1024, nullptr, esq, 1024, 1024, nullptr, nullptr, nullptr);
  k_bgemm<1, false, false><<<dim3(8, 128), blk, 0, stream>>>(
      esbf, 1024, WkB, 1024, nullptr, avbf, 1024, 1024, avtab, src_langs, src_chars);

  // ---- decoder init ----
  k_ctxinit<<<128, blk, 0, stream>>>(h, ctx, ctxbf);
  k_rec<<<48, blk, 0, stream>>>(ctxbf, WicB, gibuf, H3, 48,
                                nullptr, nullptr, nullptr, nullptr, nullptr);
  k_gates_dec<<<128, blk, 0, stream>>>(gibuf, ghbuf, dgixt, tgt_chars, dec_bh,
                                       h, hbf, 0, 1, 1);

  // ---- decoder scan: [gh + att + hc] / ctxsm / gi / gates ----
  for (int t = 0; t < Tt; ++t) {
    k_rec<<<304, blk, 0, stream>>>(hbf, WhdB, ghbuf, H3, 48,
                                   esq, h, ctx, attL, hcbf + (size_t)t * Bb * Hh);
    if (t == Tt - 1) break;
    k_ctxsm<<<dim3(8, 32), blk, 0, stream>>>(attL, avbf, ctx, ctxbf);
    k_rec<<<48, blk, 0, stream>>>(ctxbf, WicB, gibuf, H3, 48,
                                  nullptr, nullptr, nullptr, nullptr, nullptr);
    k_gates_dec<<<128, blk, 0, stream>>>(gibuf, ghbuf, dgixt, tgt_chars, dec_bh,
                                         h, hbf, t, 0, 0);
  }

  // ---- MLP: scores = relu(relu(hc@W1^T+b1)@W2^T+b2)@W3^T ----
  k_bgemm<0, true, true><<<dim3(32, 32), blk, 0, stream>>>(
      hcbf, 1024, W1B, 1024, b1, G1, 4096, 1024, nullptr, nullptr, nullptr);
  k_bgemm<0, true, true><<<dim3(16, 32), blk, 0, stream>>>(
      G1, 4096, W2B, 4096, b2, G2, 2048, 4096, nullptr, nullptr, nullptr);
  k_bgemm<2, false, false><<<dim3(1, 32), blk, 0, stream>>>(
      G2, 2048, W3B, 2048, nullptr, out, 0, 2048, nullptr, nullptr, nullptr);
}